// Round 1
// baseline (482.924 us; speedup 1.0000x reference)
//
#include <hip/hip_runtime.h>
#include <hip/hip_bf16.h>

#define H_DIM 1024
#define NE 8
#define IDIM 1408
#define SIDIM 2816
#define NTOK 2048

typedef __attribute__((ext_vector_type(8))) _Float16 half8;
typedef __attribute__((ext_vector_type(4))) float f32x4;

// ---------------------------------------------------------------- convert
__global__ __launch_bounds__(256) void cvt_kernel(const float* __restrict__ src,
                                                  _Float16* __restrict__ dst) {
    size_t i = ((size_t)blockIdx.x * 256 + threadIdx.x) * 8;
    float4 a = *(const float4*)(src + i);
    float4 b = *(const float4*)(src + i + 4);
    half8 o;
    o[0] = (_Float16)a.x; o[1] = (_Float16)a.y; o[2] = (_Float16)a.z; o[3] = (_Float16)a.w;
    o[4] = (_Float16)b.x; o[5] = (_Float16)b.y; o[6] = (_Float16)b.z; o[7] = (_Float16)b.w;
    *(half8*)(dst + i) = o;
}

// ---------------------------------------------------------------- router
// One wave per token: 8 expert logits + shared-expert gate logit, fp32.
__global__ __launch_bounds__(256) void router_kernel(
    const float* __restrict__ x, const float* __restrict__ gate_w,
    const float* __restrict__ seg_w, float* __restrict__ wbuf,
    float* __restrict__ swbuf) {
    const int wave = threadIdx.x >> 6, lane = threadIdx.x & 63;
    const int n = blockIdx.x * 4 + wave;
    const float* xr = x + (size_t)n * H_DIM;
    float4 xv[4];
#pragma unroll
    for (int i = 0; i < 4; ++i) xv[i] = *(const float4*)(xr + i * 256 + lane * 4);
    float logits[9];
    for (int e = 0; e < 9; ++e) {
        const float* wr = (e < 8) ? (gate_w + (size_t)e * H_DIM) : seg_w;
        float p = 0.f;
#pragma unroll
        for (int i = 0; i < 4; ++i) {
            float4 wv = *(const float4*)(wr + i * 256 + lane * 4);
            p += xv[i].x * wv.x + xv[i].y * wv.y + xv[i].z * wv.z + xv[i].w * wv.w;
        }
#pragma unroll
        for (int m = 32; m > 0; m >>= 1) p += __shfl_xor(p, m, 64);
        logits[e] = p;
    }
    float mx = logits[0];
#pragma unroll
    for (int e = 1; e < 8; ++e) mx = fmaxf(mx, logits[e]);
    float pe[8], s = 0.f;
#pragma unroll
    for (int e = 0; e < 8; ++e) { pe[e] = expf(logits[e] - mx); s += pe[e]; }
    int i1 = 0;
#pragma unroll
    for (int e = 1; e < 8; ++e) if (logits[e] > logits[i1]) i1 = e;   // strict >: first max (top_k tie rule)
    int i2 = -1;
#pragma unroll
    for (int e = 0; e < 8; ++e) {
        if (e == i1) continue;
        if (i2 < 0 || logits[e] > logits[i2]) i2 = e;
    }
    if (lane < 8) wbuf[n * NE + lane] = (lane == i1 || lane == i2) ? pe[lane] / s : 0.f;
    if (lane == 8) swbuf[n] = 1.f / (1.f + expf(-logits[8]));
}

// ---------------------------------------------------------------- per-expert token lists
// 8 waves, wave e scans all tokens in order -> sorted, deterministic lists.
__global__ __launch_bounds__(512) void build_lists_kernel(
    const float* __restrict__ wbuf, int* __restrict__ list, int* __restrict__ cnt) {
    const int e = threadIdx.x >> 6, lane = threadIdx.x & 63;
    int base = 0;
    for (int n0 = 0; n0 < NTOK; n0 += 64) {
        float v = wbuf[(size_t)(n0 + lane) * NE + e];
        unsigned long long m = __ballot(v > 0.f);
        int pre = __popcll(m & ((1ull << lane) - 1ull));
        if (v > 0.f) list[e * NTOK + base + pre] = n0 + lane;
        base += __popcll(m);
    }
    if (lane == 0) cnt[e] = base;
}

// ---------------------------------------------------------------- GEMM1 (gate+up fused, silu, scale, ->f16 h)
// MODE 0: sparse per-expert (gather rows via list, scale = w[tok][e], out hm[e][slot][I])
// MODE 1: dense shared expert (scale = sigmoid gate, out hs[tok][SI])
// Tile: BM=128, BN=64 (dual B: gate rows + up rows), BK=64. 4 waves (2x2), wave = 64x32.
template <int MODE>
__global__ __launch_bounds__(256) void gemm1_kernel(
    const _Float16* __restrict__ xb, const _Float16* __restrict__ Bg0,
    const _Float16* __restrict__ Bu0, const float* __restrict__ scale,
    const int* __restrict__ list, const int* __restrict__ cnt,
    _Float16* __restrict__ hout) {
    const int e = blockIdx.z;
    const int n0 = blockIdx.x * 64;
    const int m0 = blockIdx.y * 128;
    int count;
    const _Float16 *Bg, *Bu;
    _Float16* out;
    int outStride;
    if (MODE == 0) {
        count = cnt[e];
        if (m0 >= count) return;
        Bg = Bg0 + (size_t)e * (2 * IDIM * H_DIM) + (size_t)n0 * H_DIM;
        Bu = Bg + (size_t)IDIM * H_DIM;
        out = hout + (size_t)e * NTOK * IDIM;
        outStride = IDIM;
    } else {
        count = NTOK;
        Bg = Bg0 + (size_t)n0 * H_DIM;
        Bu = Bu0 + (size_t)n0 * H_DIM;
        out = hout;
        outStride = SIDIM;
    }
    __shared__ __align__(16) _Float16 As[128 * 64];
    __shared__ __align__(16) _Float16 Bgs[64 * 64];
    __shared__ __align__(16) _Float16 Bus[64 * 64];
    __shared__ int toks[128];
    const int tid = threadIdx.x;
    if (tid < 128) {
        int slot = m0 + tid;
        toks[tid] = (MODE == 0) ? list[e * NTOK + (slot < count ? slot : count - 1)] : slot;
    }
    __syncthreads();
    const int lane = tid & 63, wv = tid >> 6;
    const int wr = wv >> 1, wc = wv & 1;
    const int fr = lane & 15, fk = (lane >> 4) * 8;
    f32x4 accg[4][2] = {};
    f32x4 accu[4][2] = {};
    for (int k0 = 0; k0 < H_DIM; k0 += 64) {
#pragma unroll
        for (int it = 0; it < 4; ++it) {
            int c = it * 256 + tid;
            int row = c >> 3, col = (c & 7) << 3;
            *(half8*)&As[row * 64 + col] =
                *(const half8*)(xb + (size_t)toks[row] * H_DIM + k0 + col);
        }
#pragma unroll
        for (int it = 0; it < 2; ++it) {
            int c = it * 256 + tid;
            int row = c >> 3, col = (c & 7) << 3;
            *(half8*)&Bgs[row * 64 + col] = *(const half8*)(Bg + (size_t)row * H_DIM + k0 + col);
            *(half8*)&Bus[row * 64 + col] = *(const half8*)(Bu + (size_t)row * H_DIM + k0 + col);
        }
        __syncthreads();
#pragma unroll
        for (int kk = 0; kk < 2; ++kk) {
            half8 af[4], bgf[2], buf2[2];
#pragma unroll
            for (int mi = 0; mi < 4; ++mi)
                af[mi] = *(const half8*)&As[(wr * 64 + mi * 16 + fr) * 64 + kk * 32 + fk];
#pragma unroll
            for (int ni = 0; ni < 2; ++ni) {
                bgf[ni] = *(const half8*)&Bgs[(wc * 32 + ni * 16 + fr) * 64 + kk * 32 + fk];
                buf2[ni] = *(const half8*)&Bus[(wc * 32 + ni * 16 + fr) * 64 + kk * 32 + fk];
            }
#pragma unroll
            for (int mi = 0; mi < 4; ++mi)
#pragma unroll
                for (int ni = 0; ni < 2; ++ni) {
                    accg[mi][ni] = __builtin_amdgcn_mfma_f32_16x16x32_f16(af[mi], bgf[ni],
                                                                          accg[mi][ni], 0, 0, 0);
                    accu[mi][ni] = __builtin_amdgcn_mfma_f32_16x16x32_f16(af[mi], buf2[ni],
                                                                          accu[mi][ni], 0, 0, 0);
                }
        }
        __syncthreads();
    }
    const int j4 = (lane >> 4) * 4;
#pragma unroll
    for (int mi = 0; mi < 4; ++mi) {
#pragma unroll
        for (int j = 0; j < 4; ++j) {
            int r = wr * 64 + mi * 16 + j4 + j;
            int slot = m0 + r;
            float sc;
            if (MODE == 0)
                sc = (slot < count) ? scale[(size_t)toks[r] * NE + e] : 0.f;
            else
                sc = scale[slot];
#pragma unroll
            for (int ni = 0; ni < 2; ++ni) {
                float g = accg[mi][ni][j];
                float u = accu[mi][ni][j];
                float hv = sc * (g / (1.f + expf(-g))) * u;
                out[(size_t)slot * outStride + n0 + wc * 32 + ni * 16 + fr] = (_Float16)hv;
            }
        }
    }
}

// ---------------------------------------------------------------- GEMM2 shared (dense, WRITES out)
// Tile 64x64, 4 waves (2x2), wave = 32x32. K = SI.
__global__ __launch_bounds__(256) void gemm2_shared_kernel(
    const _Float16* __restrict__ hs, const _Float16* __restrict__ sd_b,
    float* __restrict__ out) {
    const int n0 = blockIdx.x * 64;
    const int m0 = blockIdx.y * 64;
    __shared__ __align__(16) _Float16 As[64 * 64];
    __shared__ __align__(16) _Float16 Bs[64 * 64];
    const int tid = threadIdx.x;
    const int lane = tid & 63, wv = tid >> 6;
    const int wr = wv >> 1, wc = wv & 1;
    const int fr = lane & 15, fk = (lane >> 4) * 8;
    f32x4 acc[2][2] = {};
    for (int k0 = 0; k0 < SIDIM; k0 += 64) {
#pragma unroll
        for (int it = 0; it < 2; ++it) {
            int c = it * 256 + tid;
            int row = c >> 3, col = (c & 7) << 3;
            *(half8*)&As[row * 64 + col] =
                *(const half8*)(hs + (size_t)(m0 + row) * SIDIM + k0 + col);
            *(half8*)&Bs[row * 64 + col] =
                *(const half8*)(sd_b + (size_t)(n0 + row) * SIDIM + k0 + col);
        }
        __syncthreads();
#pragma unroll
        for (int kk = 0; kk < 2; ++kk) {
            half8 af[2], bf[2];
#pragma unroll
            for (int mi = 0; mi < 2; ++mi)
                af[mi] = *(const half8*)&As[(wr * 32 + mi * 16 + fr) * 64 + kk * 32 + fk];
#pragma unroll
            for (int ni = 0; ni < 2; ++ni)
                bf[ni] = *(const half8*)&Bs[(wc * 32 + ni * 16 + fr) * 64 + kk * 32 + fk];
#pragma unroll
            for (int mi = 0; mi < 2; ++mi)
#pragma unroll
                for (int ni = 0; ni < 2; ++ni)
                    acc[mi][ni] = __builtin_amdgcn_mfma_f32_16x16x32_f16(af[mi], bf[ni],
                                                                         acc[mi][ni], 0, 0, 0);
        }
        __syncthreads();
    }
    const int j4 = (lane >> 4) * 4;
#pragma unroll
    for (int mi = 0; mi < 2; ++mi)
#pragma unroll
        for (int j = 0; j < 4; ++j) {
            int r = wr * 32 + mi * 16 + j4 + j;
#pragma unroll
            for (int ni = 0; ni < 2; ++ni)
                out[(size_t)(m0 + r) * H_DIM + n0 + wc * 32 + ni * 16 + fr] = acc[mi][ni][j];
        }
}

// ---------------------------------------------------------------- GEMM2 MoE (sparse, atomic scatter-add)
__global__ __launch_bounds__(256) void gemm2_moe_kernel(
    const _Float16* __restrict__ hm, const _Float16* __restrict__ down_b,
    const int* __restrict__ list, const int* __restrict__ cnt,
    float* __restrict__ out) {
    const int e = blockIdx.z;
    const int count = cnt[e];
    const int n0 = blockIdx.x * 64;
    const int m0 = blockIdx.y * 64;
    if (m0 >= count) return;
    const _Float16* A = hm + (size_t)e * NTOK * IDIM;
    const _Float16* B = down_b + (size_t)e * H_DIM * IDIM;
    __shared__ __align__(16) _Float16 As[64 * 64];
    __shared__ __align__(16) _Float16 Bs[64 * 64];
    const int tid = threadIdx.x;
    const int lane = tid & 63, wv = tid >> 6;
    const int wr = wv >> 1, wc = wv & 1;
    const int fr = lane & 15, fk = (lane >> 4) * 8;
    f32x4 acc[2][2] = {};
    for (int k0 = 0; k0 < IDIM; k0 += 64) {
#pragma unroll
        for (int it = 0; it < 2; ++it) {
            int c = it * 256 + tid;
            int row = c >> 3, col = (c & 7) << 3;
            *(half8*)&As[row * 64 + col] =
                *(const half8*)(A + (size_t)(m0 + row) * IDIM + k0 + col);
            *(half8*)&Bs[row * 64 + col] =
                *(const half8*)(B + (size_t)(n0 + row) * IDIM + k0 + col);
        }
        __syncthreads();
#pragma unroll
        for (int kk = 0; kk < 2; ++kk) {
            half8 af[2], bf[2];
#pragma unroll
            for (int mi = 0; mi < 2; ++mi)
                af[mi] = *(const half8*)&As[(wr * 32 + mi * 16 + fr) * 64 + kk * 32 + fk];
#pragma unroll
            for (int ni = 0; ni < 2; ++ni)
                bf[ni] = *(const half8*)&Bs[(wc * 32 + ni * 16 + fr) * 64 + kk * 32 + fk];
#pragma unroll
            for (int mi = 0; mi < 2; ++mi)
#pragma unroll
                for (int ni = 0; ni < 2; ++ni)
                    acc[mi][ni] = __builtin_amdgcn_mfma_f32_16x16x32_f16(af[mi], bf[ni],
                                                                         acc[mi][ni], 0, 0, 0);
        }
        __syncthreads();
    }
    const int j4 = (lane >> 4) * 4;
#pragma unroll
    for (int mi = 0; mi < 2; ++mi)
#pragma unroll
        for (int j = 0; j < 4; ++j) {
            int r = wr * 32 + mi * 16 + j4 + j;
            int slot = m0 + r;
            if (slot < count) {
                int tok = list[e * NTOK + slot];
#pragma unroll
                for (int ni = 0; ni < 2; ++ni)
                    atomicAdd(&out[(size_t)tok * H_DIM + n0 + wc * 32 + ni * 16 + fr],
                              acc[mi][ni][j]);
            }
        }
}

// ---------------------------------------------------------------- launch
extern "C" void kernel_launch(void* const* d_in, const int* in_sizes, int n_in,
                              void* d_out, int out_size, void* d_ws, size_t ws_size,
                              hipStream_t stream) {
    const float* x = (const float*)d_in[0];
    const float* gate_w = (const float*)d_in[1];
    const float* egu = (const float*)d_in[2];
    const float* edown = (const float*)d_in[3];
    const float* sgw = (const float*)d_in[4];
    const float* suw = (const float*)d_in[5];
    const float* sdw = (const float*)d_in[6];
    const float* segw = (const float*)d_in[7];
    float* out = (float*)d_out;

    _Float16* xb = (_Float16*)d_ws;
    _Float16* gu_b = xb + (size_t)NTOK * H_DIM;
    _Float16* down_b = gu_b + (size_t)NE * 2 * IDIM * H_DIM;
    _Float16* sg_b = down_b + (size_t)NE * H_DIM * IDIM;
    _Float16* su_b = sg_b + (size_t)SIDIM * H_DIM;
    _Float16* sd_b = su_b + (size_t)SIDIM * H_DIM;
    _Float16* hm = sd_b + (size_t)H_DIM * SIDIM;
    _Float16* hs = hm + (size_t)NE * NTOK * IDIM;
    float* wbuf = (float*)(hs + (size_t)NTOK * SIDIM);
    float* swbuf = wbuf + NTOK * NE;
    int* cnt = (int*)(swbuf + NTOK);
    int* list = cnt + NE;

    dim3 blk(256);
    cvt_kernel<<<(NTOK * H_DIM) / 2048, blk, 0, stream>>>(x, xb);
    cvt_kernel<<<(NE * 2 * IDIM * H_DIM) / 2048, blk, 0, stream>>>(egu, gu_b);
    cvt_kernel<<<(NE * H_DIM * IDIM) / 2048, blk, 0, stream>>>(edown, down_b);
    cvt_kernel<<<(SIDIM * H_DIM) / 2048, blk, 0, stream>>>(sgw, sg_b);
    cvt_kernel<<<(SIDIM * H_DIM) / 2048, blk, 0, stream>>>(suw, su_b);
    cvt_kernel<<<(H_DIM * SIDIM) / 2048, blk, 0, stream>>>(sdw, sd_b);
    router_kernel<<<NTOK / 4, blk, 0, stream>>>(x, gate_w, segw, wbuf, swbuf);
    build_lists_kernel<<<1, 512, 0, stream>>>(wbuf, list, cnt);
    gemm1_kernel<0><<<dim3(IDIM / 64, NTOK / 128, NE), blk, 0, stream>>>(
        xb, gu_b, nullptr, wbuf, list, cnt, hm);
    gemm1_kernel<1><<<dim3(SIDIM / 64, NTOK / 128, 1), blk, 0, stream>>>(
        xb, sg_b, su_b, swbuf, list, cnt, hs);
    gemm2_shared_kernel<<<dim3(H_DIM / 64, NTOK / 64), blk, 0, stream>>>(hs, sd_b, out);
    gemm2_moe_kernel<<<dim3(H_DIM / 64, NTOK / 64, NE), blk, 0, stream>>>(
        hm, down_b, list, cnt, out);
    (void)in_sizes; (void)n_in; (void)out_size; (void)ws_size;
}